// Round 2
// 3143.350 us; speedup vs baseline: 1.1356x; 1.1356x over previous
//
#include <hip/hip_runtime.h>
#include <math.h>

// MD-LSTM, 32x32 grid, B=128, HID=256, gates=1024.
// Diagonal wavefront: 63 launches; cells on diag d depend only on diag d-1.
//
// ACCURACY: whole recurrence in fp64 (fp32 trajectories diverge past the
// 1.945e-2 threshold). GEMM on v_mfma_f64_16x16x4f64 (matrix pipe, runs
// parallel to VALU; same fp64 accumulate, only summation order changes).
//
// R1 failed with absmax 1.8 and a fully self-consistent index derivation ->
// prime suspect is the f64 MFMA D-fragment layout (never HW-verified on
// gfx950; the dtype-independence result covers only K=32/K=16 low-precision
// shapes). This version PROBES the layout at runtime with a basis-vector
// MFMA (D = 4*E[1][2]); the hit position distinguishes the 4 plausible
// mappings:
//   d0: col=lane&15, row=4*(lane>>4)+reg   -> 4.0 at (lane 2,  reg 1)
//   d1: col=lane&15, row=(lane>>4)+4*reg   -> 4.0 at (lane 18, reg 0)
//   d2: row=lane&15, col=4*(lane>>4)+reg   -> 4.0 at (lane 1,  reg 2)
//   d3: row=lane&15, col=(lane>>4)+4*reg   -> 4.0 at (lane 33, reg 0)
// A magnitude check (sum|D| == 4.0 over the wave) guards against anything
// else; on no-match the block falls back to a VALU-FMA path over the same
// LDS tiles (correct, old-kernel-class speed). MfmaUtil in the counters
// reveals which path ran.
//
// Block = (cell, b-quarter(32), ktile(32 gate cols x 4 gates));
// id%8 == ktile keeps each XCD's W slice L2-resident across launches.
// Per block: gates[32 b][128 phi] = A[32][256] x W^T, phi -> g*256+k0+j.
// 4 waves: wave = 16 b x 64 phi = 1 b-tile x 4 f-tiles of 16x16.
//
// LDS (32 KB, unioned):
//   stage: A[k=32][rowRot=32] f64, rot slot (row+k)&31 (conflict-free frag
//          reads; naive [row][k] would be 16-way conflicted)
//          W[k=32][136] f32 (+8 pad)
//   gates: G[phi=128][rot 32] f64 after the K-loop.

#define HIMG 32
#define WIMG 32
#define BATCH 128
#define HID 256
#define BH (BATCH * HID)
#define SLAB (32 * 128 * 256)

#define WSTRIDE 136  // floats per k-row of W_lds (128 + 8 pad)

typedef double f64x4 __attribute__((ext_vector_type(4)));

__global__ __launch_bounds__(256, 4)
void mdlstm_diag_kernel(const float* __restrict__ x,
                        const float* __restrict__ wih,
                        const float* __restrict__ whh,
                        const float* __restrict__ bias,
                        float* __restrict__ out,
                        double* __restrict__ hbuf,   // [2][32][128][256]
                        double* __restrict__ sbuf,   // [2][32][128][256]
                        int d, int rlo)
{
    __shared__ double lds[4096];             // 32 KB
    double* A_lds = lds;                     // [k=32][rowRot=32]   8 KB
    float*  W_lds = (float*)(lds + 1024);    // [k=32][WSTRIDE=136] 17 KB
    double* G_lds = lds;                     // [phi=128][rot=32]  32 KB (after K-loop)

    const int tid = threadIdx.x;
    const int id  = blockIdx.x;
    const int cellIdx = id >> 5;
    const int tileIdx = id & 31;
    const int ktile = tileIdx & 7;           // == id % 8 -> XCD-stable W slice
    const int b4    = tileIdx >> 3;
    const int k0 = ktile * 32;
    const int b0 = b4 * 32;

    const int r = rlo + cellIdx;
    const int c = d - r;
    const int rc = r * WIMG + c;

    const int prev = (d & 1) ^ 1;
    const int cur  = d & 1;
    const double* hp = hbuf + (size_t)prev * SLAB;
    const double* sp = sbuf + (size_t)prev * SLAB;
    double* hc = hbuf + (size_t)cur * SLAB;
    double* sc = sbuf + (size_t)cur * SLAB;

    const bool has_up   = (r > 0);
    const bool has_left = (c > 0);
    const double* hu = hp + (size_t)(r - 1) * BH;  // valid iff has_up
    const double* hl = hp + (size_t)r * BH;        // valid iff has_left

    // ---- wave / lane geometry ----
    const int lane = tid & 63;
    const int wid  = tid >> 6;
    const int wb0  = (wid & 1) * 16;         // wave's batch offset in block
    const int wf0  = (wid >> 1) * 64;        // wave's phi offset in block
    const int cc   = lane & 15;              // 16-dim index within fragment
    const int gg   = lane >> 4;              // lane group (k sub-index)

    // ---- D-layout probe (once per block; ~1 MFMA) ----
    int layout;
    {
        double pa = (cc == 1) ? 1.0 : 0.0;   // A row 1 = ones over k
        double pb = (cc == 2) ? 1.0 : 0.0;   // B col 2 = ones over k
        f64x4 pc = {0.0, 0.0, 0.0, 0.0};
        pc = __builtin_amdgcn_mfma_f64_16x16x4f64(pa, pb, pc, 0, 0, 0);
        double s = fabs(pc[0]) + fabs(pc[1]) + fabs(pc[2]) + fabs(pc[3]);
        #pragma unroll
        for (int off = 32; off > 0; off >>= 1) s += __shfl_xor(s, off, 64);
        unsigned long long h0 = __ballot(lane == 2  && pc[1] == 4.0);
        unsigned long long h1 = __ballot(lane == 18 && pc[0] == 4.0);
        unsigned long long h2 = __ballot(lane == 1  && pc[2] == 4.0);
        unsigned long long h3 = __ballot(lane == 33 && pc[0] == 4.0);
        layout = -1;
        if (s == 4.0) {
            if (h0) layout = 0;
            else if (h1) layout = 1;
            else if (h2) layout = 2;
            else if (h3) layout = 3;
        }
    }
    const bool use_mfma = (layout >= 0);

    // ---- staging maps ----
    // A: thread loads double2 at (row=tid>>4, k=2*(tid&15)) and row+16.
    const int a_row = tid >> 4;
    const int a_kp  = tid & 15;
    const size_t ga0 = (size_t)(b0 + a_row) * HID + 2 * a_kp;
    const size_t ga1 = ga0 + (size_t)16 * HID;
    // W: p in 0..3: u=tid+p*256; phi=u>>3 (0..127), kq=u&7; float4 along k.
    const float* w_src[4];
    int w_phi[4], w_kq[4];
    #pragma unroll
    for (int p = 0; p < 4; p++) {
        int u = tid + p * 256;
        int phi = u >> 3, kq = u & 7;
        int F = (phi >> 5) * 256 + k0 + (phi & 31);   // global gate row
        w_src[p] = whh + (size_t)F * HID + 4 * kq;
        w_phi[p] = phi; w_kq[p] = kq;
    }

    f64x4 acc[4];
    #pragma unroll
    for (int ft = 0; ft < 4; ft++) acc[ft] = (f64x4){0.0, 0.0, 0.0, 0.0};

    // ---- prefetch chunk 0 ----
    double2 pu0, pu1, pl0, pl1;
    float4 pw[4];
    {
        const double2 z = {0.0, 0.0};
        pu0 = has_up   ? *(const double2*)(hu + ga0) : z;
        pu1 = has_up   ? *(const double2*)(hu + ga1) : z;
        pl0 = has_left ? *(const double2*)(hl + ga0) : z;
        pl1 = has_left ? *(const double2*)(hl + ga1) : z;
        #pragma unroll
        for (int p = 0; p < 4; p++)
            pw[p] = *(const float4*)(w_src[p]);
    }

    for (int ck = 0; ck < 8; ck++) {
        __syncthreads();                  // previous compute done reading LDS
        {
            const int k = 2 * a_kp;
            const double s0x = pu0.x + pl0.x, s0y = pu0.y + pl0.y;
            const double s1x = pu1.x + pl1.x, s1y = pu1.y + pl1.y;
            A_lds[ k      * 32 + ((a_row      + k    ) & 31)] = s0x;
            A_lds[(k + 1) * 32 + ((a_row      + k + 1) & 31)] = s0y;
            A_lds[ k      * 32 + ((a_row + 16 + k    ) & 31)] = s1x;
            A_lds[(k + 1) * 32 + ((a_row + 16 + k + 1) & 31)] = s1y;
        }
        #pragma unroll
        for (int p = 0; p < 4; p++) {
            const int kb = 4 * w_kq[p];
            W_lds[(kb + 0) * WSTRIDE + w_phi[p]] = pw[p].x;
            W_lds[(kb + 1) * WSTRIDE + w_phi[p]] = pw[p].y;
            W_lds[(kb + 2) * WSTRIDE + w_phi[p]] = pw[p].z;
            W_lds[(kb + 3) * WSTRIDE + w_phi[p]] = pw[p].w;
        }
        __syncthreads();                  // LDS ready

        if (ck < 7) {                     // prefetch next chunk during compute
            const int kg = (ck + 1) * 32;
            const double2 z = {0.0, 0.0};
            pu0 = has_up   ? *(const double2*)(hu + ga0 + kg) : z;
            pu1 = has_up   ? *(const double2*)(hu + ga1 + kg) : z;
            pl0 = has_left ? *(const double2*)(hl + ga0 + kg) : z;
            pl1 = has_left ? *(const double2*)(hl + ga1 + kg) : z;
            #pragma unroll
            for (int p = 0; p < 4; p++)
                pw[p] = *(const float4*)(w_src[p] + kg);
        }

        if (use_mfma) {
            // ---- MFMA inner loop: 8 k-steps x 4 f-tiles ----
            #pragma unroll
            for (int t = 0; t < 8; t++) {
                const int kq = t * 4 + gg;                   // k within chunk
                const double aval = A_lds[kq * 32 + ((wb0 + cc + kq) & 31)];
                const float* wrow = &W_lds[kq * WSTRIDE + wf0 + cc];
                #pragma unroll
                for (int ft = 0; ft < 4; ft++) {
                    const double bval = (double)wrow[ft * 16];
                    acc[ft] = __builtin_amdgcn_mfma_f64_16x16x4f64(aval, bval, acc[ft], 0, 0, 0);
                }
            }
        } else {
            // ---- VALU fallback (d0 thread mapping: row=wb0+4*gg+b, col=cc) ----
            for (int k = 0; k < 32; k++) {
                double av[4], wv4[4];
                #pragma unroll
                for (int b = 0; b < 4; b++)
                    av[b] = A_lds[k * 32 + ((wb0 + 4 * gg + b + k) & 31)];
                #pragma unroll
                for (int ft = 0; ft < 4; ft++)
                    wv4[ft] = (double)W_lds[k * WSTRIDE + wf0 + ft * 16 + cc];
                #pragma unroll
                for (int ft = 0; ft < 4; ft++)
                    #pragma unroll
                    for (int b = 0; b < 4; b++)
                        acc[ft][b] = fma(av[b], wv4[ft], acc[ft][b]);
            }
        }
    }

    // ---- gates -> LDS (layout-generic D-frag scatter; rot swizzle) ----
    __syncthreads();                      // done reading stage LDS
    const int slay = use_mfma ? layout : 0;
    #pragma unroll
    for (int ft = 0; ft < 4; ft++) {
        #pragma unroll
        for (int b = 0; b < 4; b++) {
            const int rA = (slay & 1) ? (gg + 4 * b) : (4 * gg + b);
            const int m  = (slay >= 2) ? cc : rA;   // local batch row (0..15)
            const int n  = (slay >= 2) ? rA : cc;   // local phi (0..15)
            const int phi  = wf0 + ft * 16 + n;
            const int brow = wb0 + m;
            G_lds[phi * 32 + ((brow + phi) & 31)] = acc[ft][b];
        }
    }
    __syncthreads();

    // ---- fused epilogue (all fp64) ----
    const int ec = tid & 31;              // k-col within ktile
    const int eb = tid >> 5;              // 0..7
    const int k = k0 + ec;
    double wv[4], bv[4];
    #pragma unroll
    for (int g = 0; g < 4; g++) {
        wv[g] = (double)wih[g * 256 + k];
        bv[g] = (double)bias[g * 256 + k];
    }
    #pragma unroll
    for (int i = 0; i < 4; i++) {
        const int bl = eb + 8 * i;
        const int b = b0 + bl;
        double gate[4];
        #pragma unroll
        for (int g = 0; g < 4; g++) {
            const int phi = g * 32 + ec;
            gate[g] = G_lds[phi * 32 + ((bl + phi) & 31)];
        }
        const double xp = (double)x[b * (HIMG * WIMG) + rc];
        const double su = has_up   ? sp[(size_t)(r - 1) * BH + b * HID + k] : 0.0;
        const double sl = has_left ? sp[(size_t)r * BH + b * HID + k]       : 0.0;
        const double gi = gate[0] + xp * wv[0] + bv[0];
        const double gf = gate[1] + xp * wv[1] + bv[1];
        const double gg2 = gate[2] + xp * wv[2] + bv[2];
        const double go = gate[3] + xp * wv[3] + bv[3];
        const double iv = 1.0 / (1.0 + exp(-gi));
        const double fv = 1.0 / (1.0 + exp(-gf));
        const double gv = tanh(gg2);
        const double ov = 1.0 / (1.0 + exp(-go));
        const double sv = fv * (su + sl) + iv * gv;
        const double hv = ov * tanh(sv);
        sc[(size_t)r * BH + b * HID + k] = sv;
        hc[(size_t)r * BH + b * HID + k] = hv;
        out[(size_t)b * (HIMG * WIMG * HID) + (size_t)rc * HID + k] = (float)hv;
    }
}

extern "C" void kernel_launch(void* const* d_in, const int* in_sizes, int n_in,
                              void* d_out, int out_size, void* d_ws, size_t ws_size,
                              hipStream_t stream) {
    const float* x    = (const float*)d_in[0];   // (128, 1024)
    const float* wih  = (const float*)d_in[1];   // (1024, 1)
    const float* whh  = (const float*)d_in[2];   // (1024, 256)
    const float* bias = (const float*)d_in[3];   // (1024,)
    float* out = (float*)d_out;                  // (128, 32*32*256)

    double* hbuf = (double*)d_ws;                // [2][32][128][256] dbl = 16.8 MB
    double* sbuf = hbuf + (size_t)2 * SLAB;      // 16.8 MB  (ws usage ~33.6 MB)

    for (int d = 0; d < HIMG + WIMG - 1; d++) {
        int rlo = d - (WIMG - 1); if (rlo < 0) rlo = 0;
        int rhi = d < (HIMG - 1) ? d : (HIMG - 1);
        int nc = rhi - rlo + 1;
        mdlstm_diag_kernel<<<dim3(nc * 32), 256, 0, stream>>>(
            x, wih, whh, bias, out, hbuf, sbuf, d, rlo);
    }
}

// Round 3
// 3112.010 us; speedup vs baseline: 1.1471x; 1.0101x over previous
//
#include <hip/hip_runtime.h>
#include <hip/hip_cooperative_groups.h>
#include <math.h>

// MD-LSTM, 32x32 grid, B=128, HID=256, gates=1024.
//
// R2 result: f64-MFMA diagonal kernel passed, total 3143 us, every mdlstm
// dispatch < 79.5 us (out of top-5). Fixed per-launch cost (~25-35 us x 63)
// now rivals big-diagonal compute. This version fuses all 63 diagonal
// launches into ONE persistent cooperative kernel (grid = 1024 blocks =
// 256 CU x 4, grid.sync() between diagonals):
//   - kills 63x launch/ramp overhead,
//   - hoists diagonal-invariant work (layout probe, staging maps, wih/bias
//     epilogue constants) out of the serial loop,
//   - prefetches epilogue operands (x, s_up, s_left) under the G-scatter
//     barrier,
//   - restores rocprof visibility: one big dispatch = top profile entry.
// Fallback: if cooperative launch is unavailable/refused, launch the
// proven per-diagonal kernel 63x (identical to R2).
//
// ACCURACY: whole recurrence in fp64 (fp32 trajectories diverge past the
// 1.945e-2 threshold). GEMM on v_mfma_f64_16x16x4f64; D-fragment layout
// probed at runtime with a basis-vector MFMA (4 candidate mappings; VALU
// fallback if none matches — R2 passed, so the probe resolves correctly).
//
// Block = (cell, b-quarter(32), ktile(32 gate cols x 4 gates));
// bid%8 == ktile keeps each XCD's W slice L2-resident for the whole run.
// Per block: gates[32 b][128 phi] = A[32][256] x W^T, phi -> g*256+k0+j.
// 4 waves: wave = 16 b x 64 phi = 1 b-tile x 4 f-tiles of 16x16.
//
// LDS (32 KB, unioned; 4 blocks/CU = 128 KB <= 160 KB):
//   stage: A[k=32][rotRow=32] f64 (rot slot (row+k)&31, conflict-free
//          frag reads), W[k=32][136] f32 (+8 pad)
//   gates: G[phi=128][rot 32] f64 after the K-loop.

#define HIMG 32
#define WIMG 32
#define BATCH 128
#define HID 256
#define BH (BATCH * HID)
#define SLAB (32 * 128 * 256)

#define WSTRIDE 136  // floats per k-row of W_lds (128 + 8 pad)

typedef double f64x4 __attribute__((ext_vector_type(4)));

namespace cg = cooperative_groups;

// ---------------------------------------------------------------------------
// Persistent cooperative kernel: all 63 diagonals, grid.sync between them.
// ---------------------------------------------------------------------------
__global__ __launch_bounds__(256, 4)
void mdlstm_persistent(const float* __restrict__ x,
                       const float* __restrict__ wih,
                       const float* __restrict__ whh,
                       const float* __restrict__ bias,
                       float* __restrict__ out,
                       double* __restrict__ hbuf,   // [2][32][128][256]
                       double* __restrict__ sbuf)   // [2][32][128][256]
{
    __shared__ double lds[4096];             // 32 KB
    double* A_lds = lds;                     // [k=32][rot=32]      8 KB
    float*  W_lds = (float*)(lds + 1024);    // [k=32][WSTRIDE] f32 17 KB
    double* G_lds = lds;                     // [phi=128][rot=32]  32 KB

    const int tid = threadIdx.x;
    const int bid = blockIdx.x;
    const int cellSlot = bid >> 5;           // 0..31
    const int tileIdx = bid & 31;
    const int ktile = tileIdx & 7;           // == bid % 8 -> XCD-stable W slice
    const int b4    = tileIdx >> 3;
    const int k0 = ktile * 32;
    const int b0 = b4 * 32;

    // ---- wave / lane geometry ----
    const int lane = tid & 63;
    const int wid  = tid >> 6;
    const int wb0  = (wid & 1) * 16;
    const int wf0  = (wid >> 1) * 64;
    const int cc   = lane & 15;
    const int gg   = lane >> 4;

    // ---- D-layout probe (ONCE for the whole run) ----
    int layout;
    {
        double pa = (cc == 1) ? 1.0 : 0.0;
        double pb = (cc == 2) ? 1.0 : 0.0;
        f64x4 pc = {0.0, 0.0, 0.0, 0.0};
        pc = __builtin_amdgcn_mfma_f64_16x16x4f64(pa, pb, pc, 0, 0, 0);
        double s = fabs(pc[0]) + fabs(pc[1]) + fabs(pc[2]) + fabs(pc[3]);
        #pragma unroll
        for (int off = 32; off > 0; off >>= 1) s += __shfl_xor(s, off, 64);
        unsigned long long h0 = __ballot(lane == 2  && pc[1] == 4.0);
        unsigned long long h1 = __ballot(lane == 18 && pc[0] == 4.0);
        unsigned long long h2 = __ballot(lane == 1  && pc[2] == 4.0);
        unsigned long long h3 = __ballot(lane == 33 && pc[0] == 4.0);
        layout = -1;
        if (s == 4.0) {
            if (h0) layout = 0;
            else if (h1) layout = 1;
            else if (h2) layout = 2;
            else if (h3) layout = 3;
        }
    }
    const bool use_mfma = (layout >= 0);
    const int slay = use_mfma ? layout : 0;

    // ---- staging maps (diagonal-invariant) ----
    const int a_row = tid >> 4;
    const int a_kp  = tid & 15;
    const size_t ga0 = (size_t)(b0 + a_row) * HID + 2 * a_kp;
    const size_t ga1 = ga0 + (size_t)16 * HID;
    const float* w_src[4];
    int w_phi[4], w_kq[4];
    #pragma unroll
    for (int p = 0; p < 4; p++) {
        int u = tid + p * 256;
        int phi = u >> 3, kq = u & 7;
        int F = (phi >> 5) * 256 + k0 + (phi & 31);
        w_src[p] = whh + (size_t)F * HID + 4 * kq;
        w_phi[p] = phi; w_kq[p] = kq;
    }

    // ---- epilogue constants (loaded ONCE) ----
    const int ec = tid & 31;
    const int eb = tid >> 5;
    const int kE = k0 + ec;
    double wvE[4], bvE[4];
    #pragma unroll
    for (int g = 0; g < 4; g++) {
        wvE[g] = (double)wih[g * 256 + kE];
        bvE[g] = (double)bias[g * 256 + kE];
    }

    cg::grid_group grid = cg::this_grid();

    for (int d = 0; d < HIMG + WIMG - 1; d++) {
        int rlo = d - (WIMG - 1); if (rlo < 0) rlo = 0;
        int rhi = d < (HIMG - 1) ? d : (HIMG - 1);
        int nc = rhi - rlo + 1;

        if (cellSlot < nc) {
            const int r = rlo + cellSlot;
            const int c = d - r;
            const int rc = r * WIMG + c;

            const int prev = (d & 1) ^ 1;
            const int cur  = d & 1;
            const double* hp = hbuf + (size_t)prev * SLAB;
            const double* sp = sbuf + (size_t)prev * SLAB;
            double* hc = hbuf + (size_t)cur * SLAB;
            double* sc = sbuf + (size_t)cur * SLAB;

            const bool has_up   = (r > 0);
            const bool has_left = (c > 0);
            const double* hu = hp + (size_t)(r - 1) * BH;
            const double* hl = hp + (size_t)r * BH;

            f64x4 acc[4];
            #pragma unroll
            for (int ft = 0; ft < 4; ft++) acc[ft] = (f64x4){0.0, 0.0, 0.0, 0.0};

            // ---- prefetch chunk 0 ----
            double2 pu0, pu1, pl0, pl1;
            float4 pw[4];
            {
                const double2 z = {0.0, 0.0};
                pu0 = has_up   ? *(const double2*)(hu + ga0) : z;
                pu1 = has_up   ? *(const double2*)(hu + ga1) : z;
                pl0 = has_left ? *(const double2*)(hl + ga0) : z;
                pl1 = has_left ? *(const double2*)(hl + ga1) : z;
                #pragma unroll
                for (int p = 0; p < 4; p++)
                    pw[p] = *(const float4*)(w_src[p]);
            }

            for (int ck = 0; ck < 8; ck++) {
                __syncthreads();          // previous compute done reading LDS
                {
                    const int k = 2 * a_kp;
                    const double s0x = pu0.x + pl0.x, s0y = pu0.y + pl0.y;
                    const double s1x = pu1.x + pl1.x, s1y = pu1.y + pl1.y;
                    A_lds[ k      * 32 + ((a_row      + k    ) & 31)] = s0x;
                    A_lds[(k + 1) * 32 + ((a_row      + k + 1) & 31)] = s0y;
                    A_lds[ k      * 32 + ((a_row + 16 + k    ) & 31)] = s1x;
                    A_lds[(k + 1) * 32 + ((a_row + 16 + k + 1) & 31)] = s1y;
                }
                #pragma unroll
                for (int p = 0; p < 4; p++) {
                    const int kb = 4 * w_kq[p];
                    W_lds[(kb + 0) * WSTRIDE + w_phi[p]] = pw[p].x;
                    W_lds[(kb + 1) * WSTRIDE + w_phi[p]] = pw[p].y;
                    W_lds[(kb + 2) * WSTRIDE + w_phi[p]] = pw[p].z;
                    W_lds[(kb + 3) * WSTRIDE + w_phi[p]] = pw[p].w;
                }
                __syncthreads();          // LDS ready

                if (ck < 7) {             // prefetch next chunk during compute
                    const int kg = (ck + 1) * 32;
                    const double2 z = {0.0, 0.0};
                    pu0 = has_up   ? *(const double2*)(hu + ga0 + kg) : z;
                    pu1 = has_up   ? *(const double2*)(hu + ga1 + kg) : z;
                    pl0 = has_left ? *(const double2*)(hl + ga0 + kg) : z;
                    pl1 = has_left ? *(const double2*)(hl + ga1 + kg) : z;
                    #pragma unroll
                    for (int p = 0; p < 4; p++)
                        pw[p] = *(const float4*)(w_src[p] + kg);
                }

                if (use_mfma) {
                    #pragma unroll
                    for (int t = 0; t < 8; t++) {
                        const int kq = t * 4 + gg;
                        const double aval = A_lds[kq * 32 + ((wb0 + cc + kq) & 31)];
                        const float* wrow = &W_lds[kq * WSTRIDE + wf0 + cc];
                        #pragma unroll
                        for (int ft = 0; ft < 4; ft++) {
                            const double bval = (double)wrow[ft * 16];
                            acc[ft] = __builtin_amdgcn_mfma_f64_16x16x4f64(aval, bval, acc[ft], 0, 0, 0);
                        }
                    }
                } else {
                    for (int k = 0; k < 32; k++) {
                        double av[4], wv4[4];
                        #pragma unroll
                        for (int b = 0; b < 4; b++)
                            av[b] = A_lds[k * 32 + ((wb0 + 4 * gg + b + k) & 31)];
                        #pragma unroll
                        for (int ft = 0; ft < 4; ft++)
                            wv4[ft] = (double)W_lds[k * WSTRIDE + wf0 + ft * 16 + cc];
                        #pragma unroll
                        for (int ft = 0; ft < 4; ft++)
                            #pragma unroll
                            for (int b = 0; b < 4; b++)
                                acc[ft][b] = fma(av[b], wv4[ft], acc[ft][b]);
                    }
                }
            }

            // ---- epilogue operand prefetch (hides under G scatter) ----
            double xp4[4], su4[4], sl4[4];
            #pragma unroll
            for (int i = 0; i < 4; i++) {
                const int b = b0 + eb + 8 * i;
                xp4[i] = (double)x[b * (HIMG * WIMG) + rc];
                su4[i] = has_up   ? sp[(size_t)(r - 1) * BH + b * HID + kE] : 0.0;
                sl4[i] = has_left ? sp[(size_t)r * BH + b * HID + kE]       : 0.0;
            }

            // ---- gates -> LDS (layout-generic D-frag scatter) ----
            __syncthreads();              // done reading stage LDS
            #pragma unroll
            for (int ft = 0; ft < 4; ft++) {
                #pragma unroll
                for (int b = 0; b < 4; b++) {
                    const int rA = (slay & 1) ? (gg + 4 * b) : (4 * gg + b);
                    const int m  = (slay >= 2) ? cc : rA;
                    const int n  = (slay >= 2) ? rA : cc;
                    const int phi  = wf0 + ft * 16 + n;
                    const int brow = wb0 + m;
                    G_lds[phi * 32 + ((brow + phi) & 31)] = acc[ft][b];
                }
            }
            __syncthreads();

            // ---- fused epilogue (all fp64) ----
            #pragma unroll
            for (int i = 0; i < 4; i++) {
                const int bl = eb + 8 * i;
                const int b = b0 + bl;
                double gate[4];
                #pragma unroll
                for (int g = 0; g < 4; g++) {
                    const int phi = g * 32 + ec;
                    gate[g] = G_lds[phi * 32 + ((bl + phi) & 31)];
                }
                const double gi = gate[0] + xp4[i] * wvE[0] + bvE[0];
                const double gf = gate[1] + xp4[i] * wvE[1] + bvE[1];
                const double gG = gate[2] + xp4[i] * wvE[2] + bvE[2];
                const double go = gate[3] + xp4[i] * wvE[3] + bvE[3];
                const double iv = 1.0 / (1.0 + exp(-gi));
                const double fv = 1.0 / (1.0 + exp(-gf));
                const double gv = tanh(gG);
                const double ov = 1.0 / (1.0 + exp(-go));
                const double sv = fv * (su4[i] + sl4[i]) + iv * gv;
                const double hv = ov * tanh(sv);
                sc[(size_t)r * BH + b * HID + kE] = sv;
                hc[(size_t)r * BH + b * HID + kE] = hv;
                out[(size_t)b * (HIMG * WIMG * HID) + (size_t)rc * HID + kE] = (float)hv;
            }
        }

        __threadfence();                  // writes visible device-wide
        grid.sync();                      // diagonal barrier
    }
}

// ---------------------------------------------------------------------------
// Fallback: proven R2 per-diagonal kernel (63 launches), byte-identical.
// ---------------------------------------------------------------------------
__global__ __launch_bounds__(256, 4)
void mdlstm_diag_kernel(const float* __restrict__ x,
                        const float* __restrict__ wih,
                        const float* __restrict__ whh,
                        const float* __restrict__ bias,
                        float* __restrict__ out,
                        double* __restrict__ hbuf,
                        double* __restrict__ sbuf,
                        int d, int rlo)
{
    __shared__ double lds[4096];
    double* A_lds = lds;
    float*  W_lds = (float*)(lds + 1024);
    double* G_lds = lds;

    const int tid = threadIdx.x;
    const int id  = blockIdx.x;
    const int cellIdx = id >> 5;
    const int tileIdx = id & 31;
    const int ktile = tileIdx & 7;
    const int b4    = tileIdx >> 3;
    const int k0 = ktile * 32;
    const int b0 = b4 * 32;

    const int r = rlo + cellIdx;
    const int c = d - r;
    const int rc = r * WIMG + c;

    const int prev = (d & 1) ^ 1;
    const int cur  = d & 1;
    const double* hp = hbuf + (size_t)prev * SLAB;
    const double* sp = sbuf + (size_t)prev * SLAB;
    double* hc = hbuf + (size_t)cur * SLAB;
    double* sc = sbuf + (size_t)cur * SLAB;

    const bool has_up   = (r > 0);
    const bool has_left = (c > 0);
    const double* hu = hp + (size_t)(r - 1) * BH;
    const double* hl = hp + (size_t)r * BH;

    const int lane = tid & 63;
    const int wid  = tid >> 6;
    const int wb0  = (wid & 1) * 16;
    const int wf0  = (wid >> 1) * 64;
    const int cc   = lane & 15;
    const int gg   = lane >> 4;

    int layout;
    {
        double pa = (cc == 1) ? 1.0 : 0.0;
        double pb = (cc == 2) ? 1.0 : 0.0;
        f64x4 pc = {0.0, 0.0, 0.0, 0.0};
        pc = __builtin_amdgcn_mfma_f64_16x16x4f64(pa, pb, pc, 0, 0, 0);
        double s = fabs(pc[0]) + fabs(pc[1]) + fabs(pc[2]) + fabs(pc[3]);
        #pragma unroll
        for (int off = 32; off > 0; off >>= 1) s += __shfl_xor(s, off, 64);
        unsigned long long h0 = __ballot(lane == 2  && pc[1] == 4.0);
        unsigned long long h1 = __ballot(lane == 18 && pc[0] == 4.0);
        unsigned long long h2 = __ballot(lane == 1  && pc[2] == 4.0);
        unsigned long long h3 = __ballot(lane == 33 && pc[0] == 4.0);
        layout = -1;
        if (s == 4.0) {
            if (h0) layout = 0;
            else if (h1) layout = 1;
            else if (h2) layout = 2;
            else if (h3) layout = 3;
        }
    }
    const bool use_mfma = (layout >= 0);

    const int a_row = tid >> 4;
    const int a_kp  = tid & 15;
    const size_t ga0 = (size_t)(b0 + a_row) * HID + 2 * a_kp;
    const size_t ga1 = ga0 + (size_t)16 * HID;
    const float* w_src[4];
    int w_phi[4], w_kq[4];
    #pragma unroll
    for (int p = 0; p < 4; p++) {
        int u = tid + p * 256;
        int phi = u >> 3, kq = u & 7;
        int F = (phi >> 5) * 256 + k0 + (phi & 31);
        w_src[p] = whh + (size_t)F * HID + 4 * kq;
        w_phi[p] = phi; w_kq[p] = kq;
    }

    f64x4 acc[4];
    #pragma unroll
    for (int ft = 0; ft < 4; ft++) acc[ft] = (f64x4){0.0, 0.0, 0.0, 0.0};

    double2 pu0, pu1, pl0, pl1;
    float4 pw[4];
    {
        const double2 z = {0.0, 0.0};
        pu0 = has_up   ? *(const double2*)(hu + ga0) : z;
        pu1 = has_up   ? *(const double2*)(hu + ga1) : z;
        pl0 = has_left ? *(const double2*)(hl + ga0) : z;
        pl1 = has_left ? *(const double2*)(hl + ga1) : z;
        #pragma unroll
        for (int p = 0; p < 4; p++)
            pw[p] = *(const float4*)(w_src[p]);
    }

    for (int ck = 0; ck < 8; ck++) {
        __syncthreads();
        {
            const int k = 2 * a_kp;
            const double s0x = pu0.x + pl0.x, s0y = pu0.y + pl0.y;
            const double s1x = pu1.x + pl1.x, s1y = pu1.y + pl1.y;
            A_lds[ k      * 32 + ((a_row      + k    ) & 31)] = s0x;
            A_lds[(k + 1) * 32 + ((a_row      + k + 1) & 31)] = s0y;
            A_lds[ k      * 32 + ((a_row + 16 + k    ) & 31)] = s1x;
            A_lds[(k + 1) * 32 + ((a_row + 16 + k + 1) & 31)] = s1y;
        }
        #pragma unroll
        for (int p = 0; p < 4; p++) {
            const int kb = 4 * w_kq[p];
            W_lds[(kb + 0) * WSTRIDE + w_phi[p]] = pw[p].x;
            W_lds[(kb + 1) * WSTRIDE + w_phi[p]] = pw[p].y;
            W_lds[(kb + 2) * WSTRIDE + w_phi[p]] = pw[p].z;
            W_lds[(kb + 3) * WSTRIDE + w_phi[p]] = pw[p].w;
        }
        __syncthreads();

        if (ck < 7) {
            const int kg = (ck + 1) * 32;
            const double2 z = {0.0, 0.0};
            pu0 = has_up   ? *(const double2*)(hu + ga0 + kg) : z;
            pu1 = has_up   ? *(const double2*)(hu + ga1 + kg) : z;
            pl0 = has_left ? *(const double2*)(hl + ga0 + kg) : z;
            pl1 = has_left ? *(const double2*)(hl + ga1 + kg) : z;
            #pragma unroll
            for (int p = 0; p < 4; p++)
                pw[p] = *(const float4*)(w_src[p] + kg);
        }

        if (use_mfma) {
            #pragma unroll
            for (int t = 0; t < 8; t++) {
                const int kq = t * 4 + gg;
                const double aval = A_lds[kq * 32 + ((wb0 + cc + kq) & 31)];
                const float* wrow = &W_lds[kq * WSTRIDE + wf0 + cc];
                #pragma unroll
                for (int ft = 0; ft < 4; ft++) {
                    const double bval = (double)wrow[ft * 16];
                    acc[ft] = __builtin_amdgcn_mfma_f64_16x16x4f64(aval, bval, acc[ft], 0, 0, 0);
                }
            }
        } else {
            for (int k = 0; k < 32; k++) {
                double av[4], wv4[4];
                #pragma unroll
                for (int b = 0; b < 4; b++)
                    av[b] = A_lds[k * 32 + ((wb0 + 4 * gg + b + k) & 31)];
                #pragma unroll
                for (int ft = 0; ft < 4; ft++)
                    wv4[ft] = (double)W_lds[k * WSTRIDE + wf0 + ft * 16 + cc];
                #pragma unroll
                for (int ft = 0; ft < 4; ft++)
                    #pragma unroll
                    for (int b = 0; b < 4; b++)
                        acc[ft][b] = fma(av[b], wv4[ft], acc[ft][b]);
            }
        }
    }

    __syncthreads();
    const int slay = use_mfma ? layout : 0;
    #pragma unroll
    for (int ft = 0; ft < 4; ft++) {
        #pragma unroll
        for (int b = 0; b < 4; b++) {
            const int rA = (slay & 1) ? (gg + 4 * b) : (4 * gg + b);
            const int m  = (slay >= 2) ? cc : rA;
            const int n  = (slay >= 2) ? rA : cc;
            const int phi  = wf0 + ft * 16 + n;
            const int brow = wb0 + m;
            G_lds[phi * 32 + ((brow + phi) & 31)] = acc[ft][b];
        }
    }
    __syncthreads();

    const int ec = tid & 31;
    const int eb = tid >> 5;
    const int k = k0 + ec;
    double wv[4], bv[4];
    #pragma unroll
    for (int g = 0; g < 4; g++) {
        wv[g] = (double)wih[g * 256 + k];
        bv[g] = (double)bias[g * 256 + k];
    }
    #pragma unroll
    for (int i = 0; i < 4; i++) {
        const int bl = eb + 8 * i;
        const int b = b0 + bl;
        double gate[4];
        #pragma unroll
        for (int g = 0; g < 4; g++) {
            const int phi = g * 32 + ec;
            gate[g] = G_lds[phi * 32 + ((bl + phi) & 31)];
        }
        const double xp = (double)x[b * (HIMG * WIMG) + rc];
        const double su = has_up   ? sp[(size_t)(r - 1) * BH + b * HID + k] : 0.0;
        const double sl = has_left ? sp[(size_t)r * BH + b * HID + k]       : 0.0;
        const double gi = gate[0] + xp * wv[0] + bv[0];
        const double gf = gate[1] + xp * wv[1] + bv[1];
        const double gg2 = gate[2] + xp * wv[2] + bv[2];
        const double go = gate[3] + xp * wv[3] + bv[3];
        const double iv = 1.0 / (1.0 + exp(-gi));
        const double fv = 1.0 / (1.0 + exp(-gf));
        const double gv = tanh(gg2);
        const double ov = 1.0 / (1.0 + exp(-go));
        const double sv = fv * (su + sl) + iv * gv;
        const double hv = ov * tanh(sv);
        sc[(size_t)r * BH + b * HID + k] = sv;
        hc[(size_t)r * BH + b * HID + k] = hv;
        out[(size_t)b * (HIMG * WIMG * HID) + (size_t)rc * HID + k] = (float)hv;
    }
}

extern "C" void kernel_launch(void* const* d_in, const int* in_sizes, int n_in,
                              void* d_out, int out_size, void* d_ws, size_t ws_size,
                              hipStream_t stream) {
    const float* x    = (const float*)d_in[0];   // (128, 1024)
    const float* wih  = (const float*)d_in[1];   // (1024, 1)
    const float* whh  = (const float*)d_in[2];   // (1024, 256)
    const float* bias = (const float*)d_in[3];   // (1024,)
    float* out = (float*)d_out;                  // (128, 32*32*256)

    double* hbuf = (double*)d_ws;                // [2][32][128][256] dbl
    double* sbuf = hbuf + (size_t)2 * SLAB;      // ws usage ~33.6 MB

    // Decide once whether the cooperative path is viable (4 blocks/CU
    // co-residency for a 1024-block grid on 256 CUs).
    static int coop = -1;
    if (coop < 0) {
        int maxB = 0;
        hipError_t e = hipOccupancyMaxActiveBlocksPerMultiprocessor(
            &maxB, mdlstm_persistent, 256, 0);
        coop = (e == hipSuccess && maxB >= 4) ? 1 : 0;
    }

    if (coop) {
        void* args[] = {(void*)&x, (void*)&wih, (void*)&whh, (void*)&bias,
                        (void*)&out, (void*)&hbuf, (void*)&sbuf};
        hipError_t e = hipLaunchCooperativeKernel(
            mdlstm_persistent, dim3(1024), dim3(256), args, 0, stream);
        if (e == hipSuccess) return;
        coop = 0;  // fall through to per-diagonal launches
    }

    for (int d = 0; d < HIMG + WIMG - 1; d++) {
        int rlo = d - (WIMG - 1); if (rlo < 0) rlo = 0;
        int rhi = d < (HIMG - 1) ? d : (HIMG - 1);
        int nc = rhi - rlo + 1;
        mdlstm_diag_kernel<<<dim3(nc * 32), 256, 0, stream>>>(
            x, wih, whh, bias, out, hbuf, sbuf, d, rlo);
    }
}